// Round 11
// baseline (172.367 us; speedup 1.0000x reference)
//
#include <hip/hip_runtime.h>
#include <hip/hip_bf16.h>
#include <math.h>

#define BB 4
#define NN 1024
#define DIMM 256
#define HEADS 8
#define DH 64
#define INNERD 512
#define NT 16
#define MDPLANE 4194304   // B*N*N

typedef __bf16 bf16x8 __attribute__((ext_vector_type(8)));
typedef float f32x4 __attribute__((ext_vector_type(4)));

// Trans-free GELU (used by out_gemm epilogue): clamp [-3,3] + odd poly.
__device__ __forceinline__ float gelu_poly(float x) {
    float xc = fminf(fmaxf(x, -3.0f), 3.0f);
    float u = xc * xc;
    float f = fmaf(u, fmaf(u, fmaf(u, fmaf(u, 4.4413e-5f, -1.33195e-3f),
                                   1.70980e-2f), -1.299964e-1f), 7.9734583e-1f);
    float E = xc * f;
    float hx = 0.5f * xc;
    float g = fmaf(hx, E, hx);
    return g + fmaxf(x - 3.0f, 0.0f);
}

// Tanh-form GELU for dmlp: 6 VALU + 2 trans (exp on trans pipe). |err| <= ~1e-3.
// gelu(x) = x * sigmoid(2z), z = x*(0.7978845608 + 0.0356774081*x^2)
__device__ __forceinline__ float gelu_fast(float x) {
    float x2 = x * x;
    float z = x * fmaf(x2, 0.0356774081f, 0.7978845608f);
    float e = __expf(-2.0f * z);          // 1 mul + v_exp (trans)
    return __fdividef(x, 1.0f + e);       // 1 add + v_rcp (trans) + 1 mul
}
__device__ __forceinline__ float leaky_f(float x) {
    return fmaxf(x, 0.01f * x);
}

// ---------------- prep: ln rows (0..4095) | wtg Wqkv (4096..4191) | wtg Wout (4192..4223) ----------------
__global__ __launch_bounds__(256) void prep_kernel(const float* __restrict__ feat,
                                                   const float* __restrict__ gamma,
                                                   const float* __restrict__ beta,
                                                   __hip_bfloat16* __restrict__ xb,
                                                   const float* __restrict__ Wqkv,
                                                   __hip_bfloat16* __restrict__ Wt,
                                                   const float* __restrict__ Wout,
                                                   __hip_bfloat16* __restrict__ Wot) {
    __shared__ float smem[64 * 65];
    int bx = blockIdx.x;
    int tid = threadIdx.x;
    if (bx < 4096) {
        // LayerNorm row
        int row = bx;
        float v = feat[row * DIMM + tid];
        float s = v, ss = v * v;
        #pragma unroll
        for (int off = 1; off < 64; off <<= 1) {
            s += __shfl_xor(s, off);
            ss += __shfl_xor(ss, off);
        }
        float* red = smem;
        int w = tid >> 6, lane = tid & 63;
        if (lane == 0) { red[w] = s; red[4 + w] = ss; }
        __syncthreads();
        s = red[0] + red[1] + red[2] + red[3];
        ss = red[4] + red[5] + red[6] + red[7];
        float mu = s * (1.0f / DIMM);
        float var = ss * (1.0f / DIMM) - mu * mu;
        float rs = rsqrtf(var + 1e-5f);
        xb[row * DIMM + tid] = __float2bfloat16((v - mu) * rs * gamma[tid] + beta[tid]);
    } else {
        // transpose-convert W[R][C] f32 -> Wt[C][R] bf16, 64x64 tiles
        const float* W;
        __hip_bfloat16* Wd;
        int C, R, nx, ky;
        if (bx < 4192) {
            int t = bx - 4096;          // 96 tiles: 24 x 4
            W = Wqkv; Wd = Wt; C = 1536; R = 256;
            nx = t % 24; ky = t / 24;
        } else {
            int t = bx - 4192;          // 32 tiles: 4 x 8
            W = Wout; Wd = Wot; C = 256; R = 512;
            nx = t % 4; ky = t / 4;
        }
        int n0 = nx * 64, k0 = ky * 64;
        int cc = tid & 63, rr = tid >> 6;
        #pragma unroll
        for (int p = 0; p < 16; ++p) {
            int k = rr + p * 4;
            smem[k * 65 + cc] = W[(k0 + k) * C + n0 + cc];
        }
        __syncthreads();
        #pragma unroll
        for (int p = 0; p < 16; ++p) {
            int n = rr + p * 4;
            Wd[(n0 + n) * R + k0 + cc] = __float2bfloat16(smem[cc * 65 + n]);
        }
    }
}

// ---------------- fused mid: dmlp blocks (0..4095) || qkv GEMM blocks (4096..5631) ----------------
__device__ __forceinline__ void qkv_body(int bx,
                                         const __hip_bfloat16* __restrict__ xb,
                                         const __hip_bfloat16* __restrict__ Wt,
                                         __hip_bfloat16* __restrict__ qb,
                                         __hip_bfloat16* __restrict__ kb,
                                         __hip_bfloat16* __restrict__ vtb) {
    int mt = bx & 63, nt = bx >> 6;
    int tid = threadIdx.x, w = tid >> 6, lane = tid & 63;
    int g = lane >> 4, c = lane & 15;

    const __hip_bfloat16* ap = xb + (mt * 64 + w * 16 + c) * 256 + g * 8;
    bf16x8 a[8];
    #pragma unroll
    for (int ks = 0; ks < 8; ++ks) a[ks] = *reinterpret_cast<const bf16x8*>(ap + ks * 32);

    f32x4 acc[4];
    #pragma unroll
    for (int jf = 0; jf < 4; ++jf) { acc[jf][0] = 0.f; acc[jf][1] = 0.f; acc[jf][2] = 0.f; acc[jf][3] = 0.f; }

    const __hip_bfloat16* bp = Wt + (nt * 64 + c) * 256 + g * 8;
    #pragma unroll
    for (int jf = 0; jf < 4; ++jf) {
        const __hip_bfloat16* bpj = bp + jf * 16 * 256;
        #pragma unroll
        for (int ks = 0; ks < 8; ++ks) {
            bf16x8 bfrag = *reinterpret_cast<const bf16x8*>(bpj + ks * 32);
            acc[jf] = __builtin_amdgcn_mfma_f32_16x16x32_bf16(a[ks], bfrag, acc[jf], 0, 0, 0);
        }
    }

    int col0 = nt * 64;
    int part = col0 >> 9;            // 0=q,1=k,2=v
    int h = (col0 >> 6) & 7;
    #pragma unroll
    for (int jf = 0; jf < 4; ++jf) {
        int d = jf * 16 + c;
        #pragma unroll
        for (int r = 0; r < 4; ++r) {
            int m = mt * 64 + w * 16 + g * 4 + r;
            int b = m >> 10, nn = m & 1023;
            if (part == 0)
                qb[(((b * HEADS + h) * NN) + nn) * DH + d] = __float2bfloat16(acc[jf][r] * 0.125f);
            else if (part == 1)
                kb[(((b * HEADS + h) * NN) + nn) * DH + d] = __float2bfloat16(acc[jf][r]);
            else
                vtb[((long)(b * HEADS + h) * DH + d) * NN + nn] = __float2bfloat16(acc[jf][r]);
        }
    }
}

// dmlp: f32, 4 independent pair-chains (R7 structure), tanh-GELU on trans pipe,
// weights in LDS, f16 planar md output.
__device__ __forceinline__ void dmlp_body(int bi,
                                          const float* __restrict__ xyz,
                                          const float* __restrict__ w,   // LDS, 204 f32
                                          _Float16* __restrict__ md) {
    int tid = threadIdx.x;
    int b = bi >> 10;
    const float* xj = xyz + (long)b * NN * 3;
    float xi0 = xyz[bi * 3 + 0], xi1 = xyz[bi * 3 + 1], xi2 = xyz[bi * 3 + 2];

    float d0[4], d1[4], d2[4];
    #pragma unroll
    for (int p = 0; p < 4; ++p) {
        int j = tid + p * 256;
        d0[p] = xj[j * 3 + 0] - xi0;
        d1[p] = xj[j * 3 + 1] - xi1;
        d2[p] = xj[j * 3 + 2] - xi2;
    }

    float pp0[4], pp1[4], pp2[4], nv0[4], nv1[4], nv2[4];
    {   // pos branch
        float r0[4], r1[4], r2[4];
        float a0[4] = {}, a1[4] = {}, a2[4] = {};
        #pragma unroll
        for (int p = 0; p < 4; ++p) {
            r0[p] = fmaxf(d0[p], 0.f); r1[p] = fmaxf(d1[p], 0.f); r2[p] = fmaxf(d2[p], 0.f);
        }
        #pragma unroll
        for (int m = 0; m < 16; ++m) {
            float w0 = w[m], w1 = w[16 + m], w2 = w[32 + m];
            float u0 = w[48 + 3 * m], u1 = w[48 + 3 * m + 1], u2 = w[48 + 3 * m + 2];
            #pragma unroll
            for (int p = 0; p < 4; ++p) {
                float t = fmaf(r0[p], w0, fmaf(r1[p], w1, r2[p] * w2));
                t = gelu_fast(t);
                a0[p] = fmaf(t, u0, a0[p]);
                a1[p] = fmaf(t, u1, a1[p]);
                a2[p] = fmaf(t, u2, a2[p]);
            }
        }
        #pragma unroll
        for (int p = 0; p < 4; ++p) {
            pp0[p] = leaky_f(a0[p]); pp1[p] = leaky_f(a1[p]); pp2[p] = leaky_f(a2[p]);
        }
    }
    {   // neg branch
        float r0[4], r1[4], r2[4];
        float a0[4] = {}, a1[4] = {}, a2[4] = {};
        #pragma unroll
        for (int p = 0; p < 4; ++p) {
            r0[p] = fmaxf(-d0[p], 0.f); r1[p] = fmaxf(-d1[p], 0.f); r2[p] = fmaxf(-d2[p], 0.f);
        }
        #pragma unroll
        for (int m = 0; m < 16; ++m) {
            float w0 = w[96 + m], w1 = w[96 + 16 + m], w2 = w[96 + 32 + m];
            float u0 = w[144 + 3 * m], u1 = w[144 + 3 * m + 1], u2 = w[144 + 3 * m + 2];
            #pragma unroll
            for (int p = 0; p < 4; ++p) {
                float t = fmaf(r0[p], w0, fmaf(r1[p], w1, r2[p] * w2));
                t = gelu_fast(t);
                a0[p] = fmaf(t, u0, a0[p]);
                a1[p] = fmaf(t, u1, a1[p]);
                a2[p] = fmaf(t, u2, a2[p]);
            }
        }
        #pragma unroll
        for (int p = 0; p < 4; ++p) {
            nv0[p] = leaky_f(a0[p]); nv1[p] = leaky_f(a1[p]); nv2[p] = leaky_f(a2[p]);
        }
    }
    float c00 = w[192], c01 = w[193], c02 = w[194];
    float c10 = w[195], c11 = w[196], c12 = w[197];
    float c20 = w[198], c21 = w[199], c22 = w[200];
    float b0 = w[201], b1 = w[202], b2 = w[203];

    _Float16* st0 = md;
    _Float16* st1 = md + MDPLANE;
    _Float16* st2 = md + 2 * MDPLANE;
    long base = (long)bi * NN;
    #pragma unroll
    for (int p = 0; p < 4; ++p) {
        int j = tid + p * 256;
        float q0 = pp0[p] * nv0[p], q1 = pp1[p] * nv1[p], q2 = pp2[p] * nv2[p];
        float c0 = leaky_f(fmaf(q0, c00, fmaf(q1, c10, fmaf(q2, c20, b0))));
        float c1 = leaky_f(fmaf(q0, c01, fmaf(q1, c11, fmaf(q2, c21, b1))));
        float c2 = leaky_f(fmaf(q0, c02, fmaf(q1, c12, fmaf(q2, c22, b2))));
        st0[base + j] = (_Float16)(c0 * d0[p]);
        st1[base + j] = (_Float16)(c1 * d1[p]);
        st2[base + j] = (_Float16)(c2 * d2[p]);
    }
}

__global__ __launch_bounds__(256) void fused_mid(const float* __restrict__ xyz,
                                                 const float* __restrict__ Wp1,
                                                 const float* __restrict__ Wp2,
                                                 const float* __restrict__ Wn1,
                                                 const float* __restrict__ Wn2,
                                                 const float* __restrict__ Wc,
                                                 const float* __restrict__ bc,
                                                 _Float16* __restrict__ md,
                                                 const __hip_bfloat16* __restrict__ xb,
                                                 const __hip_bfloat16* __restrict__ Wt,
                                                 __hip_bfloat16* __restrict__ qb,
                                                 __hip_bfloat16* __restrict__ kb,
                                                 __hip_bfloat16* __restrict__ vtb) {
    __shared__ float wlds[204];
    int bx = blockIdx.x;
    if (bx < 4096) {
        int t = threadIdx.x;
        if (t < 204) {
            float v;
            if (t < 48) v = Wp1[t];
            else if (t < 96) v = Wp2[t - 48];
            else if (t < 144) v = Wn1[t - 96];
            else if (t < 192) v = Wn2[t - 144];
            else if (t < 201) v = Wc[t - 192];
            else v = bc[t - 201];
            wlds[t] = v;
        }
        __syncthreads();
        dmlp_body(bx, xyz, wlds, md);
    } else {
        qkv_body(bx - 4096, xb, Wt, qb, kb, vtb);
    }
}

// ---------------- K4: fused MFMA attention (f16 md, hoisted loads) ----------------
__global__ __launch_bounds__(256) void attn_kernel(
    const __hip_bfloat16* __restrict__ q,
    const __hip_bfloat16* __restrict__ kk,
    const __hip_bfloat16* __restrict__ vt,
    const _Float16* __restrict__ md,
    const float* __restrict__ Wsp,
    __hip_bfloat16* __restrict__ yb)
{
    int it = blockIdx.x, h = blockIdx.y, b = blockIdx.z;
    int tid = threadIdx.x;
    int w = tid >> 6, lane = tid & 63;
    int g = lane >> 4, c = lane & 15;

    __shared__ __align__(16) __hip_bfloat16 k_lds[2][64][64];
    __shared__ __align__(16) __hip_bfloat16 v_lds[2][64][64];   // V^T tile: [d][j]
    __shared__ __align__(16) __hip_bfloat16 p_lds[4][16][64];

    const __hip_bfloat16* qp = q + ((long)(b * HEADS + h) * NN + it * 64) * DH;
    const __hip_bfloat16* kp = kk + (long)(b * HEADS + h) * NN * DH;
    const __hip_bfloat16* vp = vt + (long)(b * HEADS + h) * DH * NN;

    bf16x8 qa[2];
    #pragma unroll
    for (int t2 = 0; t2 < 2; ++t2)
        qa[t2] = *reinterpret_cast<const bf16x8*>(qp + (w * 16 + c) * DH + t2 * 32 + g * 8);

    int r0 = tid >> 3;
    int d00 = (tid & 7) * 8;
    int4 kreg[2], vreg[2];

    f32x4 o[4];
    #pragma unroll
    for (int df = 0; df < 4; ++df) { o[df][0] = 0.f; o[df][1] = 0.f; o[df][2] = 0.f; o[df][3] = 0.f; }
    float m_[4] = {-1e30f, -1e30f, -1e30f, -1e30f};
    float l_[4] = {0.f, 0.f, 0.f, 0.f};
    float wdx[4] = {0.f, 0.f, 0.f, 0.f}, wdy[4] = {0.f, 0.f, 0.f, 0.f}, wdz[4] = {0.f, 0.f, 0.f, 0.f};

    #pragma unroll
    for (int c2 = 0; c2 < 2; ++c2) {
        int r = r0 + c2 * 32;
        kreg[c2] = *reinterpret_cast<const int4*>(kp + (0 * 64 + r) * DH + d00);
        vreg[c2] = *reinterpret_cast<const int4*>(vp + (long)r * NN + 0 * 64 + d00);
    }
    #pragma unroll
    for (int c2 = 0; c2 < 2; ++c2) {
        int r = r0 + c2 * 32;
        int sd = d00 ^ ((r & 7) << 3);
        *reinterpret_cast<int4*>(&k_lds[0][r][sd]) = kreg[c2];
        *reinterpret_cast<int4*>(&v_lds[0][r][sd]) = vreg[c2];
    }
    __syncthreads();

    const _Float16* md0 = md;
    const _Float16* md1 = md + MDPLANE;
    const _Float16* md2 = md + 2 * MDPLANE;
    long mdrow = (long)(b * NN + it * 64 + w * 16 + g * 4) * NN + c;

    for (int t = 0; t < NT; ++t) {
        int buf = t & 1;
        if (t + 1 < NT) {
            #pragma unroll
            for (int c2 = 0; c2 < 2; ++c2) {
                int r = r0 + c2 * 32;
                kreg[c2] = *reinterpret_cast<const int4*>(kp + ((t + 1) * 64 + r) * DH + d00);
                vreg[c2] = *reinterpret_cast<const int4*>(vp + (long)r * NN + (t + 1) * 64 + d00);
            }
        }

        // hoisted current-tile md loads (issue early; consumed at wdelta)
        float mdc[4][4][3];
        #pragma unroll
        for (int r = 0; r < 4; ++r) {
            long off = mdrow + (long)r * NN + t * 64;
            #pragma unroll
            for (int jf = 0; jf < 4; ++jf) {
                mdc[r][jf][0] = (float)md0[off + jf * 16];
                mdc[r][jf][1] = (float)md1[off + jf * 16];
                mdc[r][jf][2] = (float)md2[off + jf * 16];
            }
        }

        f32x4 s[4];
        #pragma unroll
        for (int jf = 0; jf < 4; ++jf) {
            f32x4 acc = {0.f, 0.f, 0.f, 0.f};
            int jl = jf * 16 + c;
            int sw = (jl & 7) << 3;
            #pragma unroll
            for (int t2 = 0; t2 < 2; ++t2) {
                bf16x8 bk = *reinterpret_cast<const bf16x8*>(&k_lds[buf][jl][(t2 * 32 + g * 8) ^ sw]);
                acc = __builtin_amdgcn_mfma_f32_16x16x32_bf16(qa[t2], bk, acc, 0, 0, 0);
            }
            s[jf] = acc;
        }

        float pe[4][4];
        #pragma unroll
        for (int r = 0; r < 4; ++r) {
            float tm = fmaxf(fmaxf(s[0][r], s[1][r]), fmaxf(s[2][r], s[3][r]));
            tm = fmaxf(tm, __shfl_xor(tm, 1));
            tm = fmaxf(tm, __shfl_xor(tm, 2));
            tm = fmaxf(tm, __shfl_xor(tm, 4));
            tm = fmaxf(tm, __shfl_xor(tm, 8));
            float nm = fmaxf(m_[r], tm);
            float corr = __expf(m_[r] - nm);
            m_[r] = nm;
            l_[r] *= corr;
            wdx[r] *= corr; wdy[r] *= corr; wdz[r] *= corr;
            o[0][r] *= corr; o[1][r] *= corr; o[2][r] *= corr; o[3][r] *= corr;
            float ps = 0.f;
            #pragma unroll
            for (int jf = 0; jf < 4; ++jf) {
                float p = __expf(s[jf][r] - nm);
                pe[r][jf] = p;
                ps += p;
            }
            l_[r] += ps;
        }

        #pragma unroll
        for (int r = 0; r < 4; ++r) {
            int row = g * 4 + r;
            int sw = (row & 7) << 3;
            #pragma unroll
            for (int jf = 0; jf < 4; ++jf)
                p_lds[w][row][(jf * 16 + c) ^ sw] = __float2bfloat16(pe[r][jf]);
        }
        asm volatile("s_waitcnt lgkmcnt(0)" ::: "memory");

        #pragma unroll
        for (int r = 0; r < 4; ++r) {
            #pragma unroll
            for (int jf = 0; jf < 4; ++jf) {
                wdx[r] = fmaf(pe[r][jf], mdc[r][jf][0], wdx[r]);
                wdy[r] = fmaf(pe[r][jf], mdc[r][jf][1], wdy[r]);
                wdz[r] = fmaf(pe[r][jf], mdc[r][jf][2], wdz[r]);
            }
        }

        #pragma unroll
        for (int t2 = 0; t2 < 2; ++t2) {
            int swp = (c & 7) << 3;
            bf16x8 pa = *reinterpret_cast<const bf16x8*>(&p_lds[w][c][(t2 * 32 + g * 8) ^ swp]);
            #pragma unroll
            for (int df = 0; df < 4; ++df) {
                int dl = df * 16 + c;
                int swv = (dl & 7) << 3;
                bf16x8 bv = *reinterpret_cast<const bf16x8*>(&v_lds[buf][dl][(t2 * 32 + g * 8) ^ swv]);
                o[df] = __builtin_amdgcn_mfma_f32_16x16x32_bf16(pa, bv, o[df], 0, 0, 0);
            }
        }

        if (t + 1 < NT) {
            #pragma unroll
            for (int c2 = 0; c2 < 2; ++c2) {
                int r = r0 + c2 * 32;
                int sd = d00 ^ ((r & 7) << 3);
                *reinterpret_cast<int4*>(&k_lds[buf ^ 1][r][sd]) = kreg[c2];
                *reinterpret_cast<int4*>(&v_lds[buf ^ 1][r][sd]) = vreg[c2];
            }
        }
        __syncthreads();
    }

    #pragma unroll
    for (int r = 0; r < 4; ++r) {
        float lv = l_[r];
        lv += __shfl_xor(lv, 1); lv += __shfl_xor(lv, 2);
        lv += __shfl_xor(lv, 4); lv += __shfl_xor(lv, 8);
        float w0 = wdx[r], w1 = wdy[r], w2 = wdz[r];
        w0 += __shfl_xor(w0, 1); w0 += __shfl_xor(w0, 2); w0 += __shfl_xor(w0, 4); w0 += __shfl_xor(w0, 8);
        w1 += __shfl_xor(w1, 1); w1 += __shfl_xor(w1, 2); w1 += __shfl_xor(w1, 4); w1 += __shfl_xor(w1, 8);
        w2 += __shfl_xor(w2, 1); w2 += __shfl_xor(w2, 2); w2 += __shfl_xor(w2, 4); w2 += __shfl_xor(w2, 8);
        float inv = 1.0f / lv;
        w0 *= inv; w1 *= inv; w2 *= inv;
        int row = g * 4 + r;
        long ig = (long)b * NN + it * 64 + w * 16 + row;
        __hip_bfloat16* yp = yb + ig * INNERD + h * DH;
        #pragma unroll
        for (int df = 0; df < 4; ++df) {
            int d = df * 16 + c;
            float disp = w0 * Wsp[d] + w1 * Wsp[64 + d] + w2 * Wsp[128 + d];
            yp[d] = __float2bfloat16(o[df][r] * inv + disp);
        }
    }
}

// ---------------- K5: MFMA output projection + GELU + residual ----------------
__global__ __launch_bounds__(256) void out_gemm(const __hip_bfloat16* __restrict__ yb,
                                                const __hip_bfloat16* __restrict__ Wot,
                                                const float* __restrict__ bout,
                                                const float* __restrict__ feat,
                                                float* __restrict__ out) {
    int mt = blockIdx.x, nt = blockIdx.y;
    int tid = threadIdx.x, w = tid >> 6, lane = tid & 63;
    int g = lane >> 4, c = lane & 15;

    const __hip_bfloat16* ap = yb + ((long)mt * 64 + w * 16 + c) * INNERD + g * 8;
    bf16x8 a[16];
    #pragma unroll
    for (int ks = 0; ks < 16; ++ks) a[ks] = *reinterpret_cast<const bf16x8*>(ap + ks * 32);

    f32x4 acc[4];
    #pragma unroll
    for (int jf = 0; jf < 4; ++jf) { acc[jf][0] = 0.f; acc[jf][1] = 0.f; acc[jf][2] = 0.f; acc[jf][3] = 0.f; }

    const __hip_bfloat16* bp = Wot + (nt * 64 + c) * INNERD + g * 8;
    #pragma unroll
    for (int jf = 0; jf < 4; ++jf) {
        const __hip_bfloat16* bpj = bp + jf * 16 * INNERD;
        #pragma unroll
        for (int ks = 0; ks < 16; ++ks) {
            bf16x8 bfrag = *reinterpret_cast<const bf16x8*>(bpj + ks * 32);
            acc[jf] = __builtin_amdgcn_mfma_f32_16x16x32_bf16(a[ks], bfrag, acc[jf], 0, 0, 0);
        }
    }

    #pragma unroll
    for (int jf = 0; jf < 4; ++jf) {
        int d = nt * 64 + jf * 16 + c;
        float bo = bout[d];
        #pragma unroll
        for (int r = 0; r < 4; ++r) {
            long m = (long)mt * 64 + w * 16 + g * 4 + r;
            float val = gelu_poly(acc[jf][r] + bo);
            out[m * DIMM + d] = val + feat[m * DIMM + d];
        }
    }
}

extern "C" void kernel_launch(void* const* d_in, const int* in_sizes, int n_in,
                              void* d_out, int out_size, void* d_ws, size_t ws_size,
                              hipStream_t stream) {
    const float* xyzs  = (const float*)d_in[0];
    const float* feat  = (const float*)d_in[1];
    const float* gamma = (const float*)d_in[2];
    const float* beta  = (const float*)d_in[3];
    const float* Wqkv  = (const float*)d_in[4];
    const float* Wp1   = (const float*)d_in[5];
    const float* Wp2   = (const float*)d_in[6];
    const float* Wn1   = (const float*)d_in[7];
    const float* Wn2   = (const float*)d_in[8];
    const float* Wc    = (const float*)d_in[9];
    const float* bc    = (const float*)d_in[10];
    const float* Wsp   = (const float*)d_in[11];
    const float* Wout  = (const float*)d_in[12];
    const float* bout  = (const float*)d_in[13];
    float* out = (float*)d_out;

    // workspace: xb 1M bf16 | Wt 384K bf16 | Wot 128K bf16 | qb/kb/vtb/yb 2M bf16 each | md 12M f16
    __hip_bfloat16* xb  = (__hip_bfloat16*)d_ws;
    __hip_bfloat16* Wt  = xb + 1048576;
    __hip_bfloat16* Wot = Wt + 393216;
    __hip_bfloat16* qb  = Wot + 131072;
    __hip_bfloat16* kb  = qb + 2097152;
    __hip_bfloat16* vtb = kb + 2097152;
    __hip_bfloat16* yb  = vtb + 2097152;
    _Float16* md = (_Float16*)(yb + 2097152);

    prep_kernel<<<4224, 256, 0, stream>>>(feat, gamma, beta, xb, Wqkv, Wt, Wout, Wot);
    fused_mid<<<5632, 256, 0, stream>>>(xyzs, Wp1, Wp2, Wn1, Wn2, Wc, bc, md,
                                        xb, Wt, qb, kb, vtb);
    attn_kernel<<<dim3(16, HEADS, BB), 256, 0, stream>>>(qb, kb, vtb, md, Wsp, yb);
    out_gemm<<<dim3(64, 4), 256, 0, stream>>>(yb, Wot, bout, feat, out);
}

// Round 12
// 123.809 us; speedup vs baseline: 1.3922x; 1.3922x over previous
//
#include <hip/hip_runtime.h>
#include <hip/hip_bf16.h>
#include <math.h>

#define BB 4
#define NN 1024
#define DIMM 256
#define HEADS 8
#define DH 64
#define INNERD 512
#define NT 16
#define MDPLANE 4194304   // B*N*N

typedef __bf16 bf16x8 __attribute__((ext_vector_type(8)));
typedef float f32x4 __attribute__((ext_vector_type(4)));
typedef _Float16 h2 __attribute__((ext_vector_type(2)));

__device__ __forceinline__ h2 h2s(float v) {
    _Float16 h = (_Float16)v;
    h2 r; r.x = h; r.y = h;
    return r;
}

// Trans-free GELU (f32, out_gemm epilogue): clamp [-3,3] + odd poly.
__device__ __forceinline__ float gelu_poly(float x) {
    float xc = fminf(fmaxf(x, -3.0f), 3.0f);
    float u = xc * xc;
    float f = fmaf(u, fmaf(u, fmaf(u, fmaf(u, 4.4413e-5f, -1.33195e-3f),
                                   1.70980e-2f), -1.299964e-1f), 7.9734583e-1f);
    float E = xc * f;
    float hx = 0.5f * xc;
    float g = fmaf(hx, E, hx);
    return g + fmaxf(x - 3.0f, 0.0f);
}

// Packed-f16 GELU (trans-free): gelu(xc) = 0.5*xc + u*f2(u), coeffs pre-halved.
__device__ __forceinline__ h2 gelu_h2(h2 x) {
    h2 xc = __builtin_elementwise_min(__builtin_elementwise_max(x, h2s(-3.0f)), h2s(3.0f));
    h2 u = xc * xc;
    h2 f = u * h2s(2.22065e-5f) + h2s(-6.65975e-4f);
    f = u * f + h2s(8.549e-3f);
    f = u * f + h2s(-6.49982e-2f);
    f = u * f + h2s(0.39867292f);
    h2 g = xc * h2s(0.5f) + u * f;
    h2 tail = __builtin_elementwise_max(x - h2s(3.0f), h2s(0.0f));
    return g + tail;
}
__device__ __forceinline__ h2 leaky_h2(h2 x) {
    return __builtin_elementwise_max(x, x * h2s(0.01f));
}

// ---------------- prep: ln (0..4095) | wtg Wqkv (4096..4191) | wtg Wout (4192..4223) | wh (4224) ----------------
__global__ __launch_bounds__(256) void prep_kernel(const float* __restrict__ feat,
                                                   const float* __restrict__ gamma,
                                                   const float* __restrict__ beta,
                                                   __hip_bfloat16* __restrict__ xb,
                                                   const float* __restrict__ Wqkv,
                                                   __hip_bfloat16* __restrict__ Wt,
                                                   const float* __restrict__ Wout,
                                                   __hip_bfloat16* __restrict__ Wot,
                                                   const float* __restrict__ Wp1,
                                                   const float* __restrict__ Wp2,
                                                   const float* __restrict__ Wn1,
                                                   const float* __restrict__ Wn2,
                                                   const float* __restrict__ Wc,
                                                   const float* __restrict__ bc,
                                                   unsigned int* __restrict__ wh) {
    __shared__ float smem[64 * 65];
    int bx = blockIdx.x;
    int tid = threadIdx.x;
    if (bx < 4096) {
        // LayerNorm row
        int row = bx;
        float v = feat[row * DIMM + tid];
        float s = v, ss = v * v;
        #pragma unroll
        for (int off = 1; off < 64; off <<= 1) {
            s += __shfl_xor(s, off);
            ss += __shfl_xor(ss, off);
        }
        float* red = smem;
        int w = tid >> 6, lane = tid & 63;
        if (lane == 0) { red[w] = s; red[4 + w] = ss; }
        __syncthreads();
        s = red[0] + red[1] + red[2] + red[3];
        ss = red[4] + red[5] + red[6] + red[7];
        float mu = s * (1.0f / DIMM);
        float var = ss * (1.0f / DIMM) - mu * mu;
        float rs = rsqrtf(var + 1e-5f);
        xb[row * DIMM + tid] = __float2bfloat16((v - mu) * rs * gamma[tid] + beta[tid]);
    } else if (bx < 4224) {
        // transpose-convert W[R][C] f32 -> Wt[C][R] bf16, 64x64 tiles
        const float* W;
        __hip_bfloat16* Wd;
        int C, R, nx, ky;
        if (bx < 4192) {
            int t = bx - 4096;          // 96 tiles: 24 x 4
            W = Wqkv; Wd = Wt; C = 1536; R = 256;
            nx = t % 24; ky = t / 24;
        } else {
            int t = bx - 4192;          // 32 tiles: 4 x 8
            W = Wout; Wd = Wot; C = 256; R = 512;
            nx = t % 4; ky = t / 4;
        }
        int n0 = nx * 64, k0 = ky * 64;
        int cc = tid & 63, rr = tid >> 6;
        #pragma unroll
        for (int p = 0; p < 16; ++p) {
            int k = rr + p * 4;
            smem[k * 65 + cc] = W[(k0 + k) * C + n0 + cc];
        }
        __syncthreads();
        #pragma unroll
        for (int p = 0; p < 16; ++p) {
            int n = rr + p * 4;
            Wd[(n0 + n) * R + k0 + cc] = __float2bfloat16(smem[cc * 65 + n]);
        }
    } else {
        // splat-convert dmlp weights to h2 uints
        // layout: [0,48) Wp1 | [48,96) Wp2 | [96,144) Wn1 | [144,192) Wn2 | [192,201) Wc | [201,204) bc
        int t = tid;
        if (t < 204) {
            float v;
            if (t < 48) v = Wp1[t];
            else if (t < 96) v = Wp2[t - 48];
            else if (t < 144) v = Wn1[t - 96];
            else if (t < 192) v = Wn2[t - 144];
            else if (t < 201) v = Wc[t - 192];
            else v = bc[t - 201];
            _Float16 h = (_Float16)v;
            unsigned short us = __builtin_bit_cast(unsigned short, h);
            wh[t] = (unsigned int)us | ((unsigned int)us << 16);
        }
    }
}

// ---------------- fused mid: dmlp blocks (0..2047, 2 rows each) || qkv GEMM (2048..3583) ----------------
__device__ __forceinline__ void qkv_body(int bx,
                                         const __hip_bfloat16* __restrict__ xb,
                                         const __hip_bfloat16* __restrict__ Wt,
                                         __hip_bfloat16* __restrict__ qb,
                                         __hip_bfloat16* __restrict__ kb,
                                         __hip_bfloat16* __restrict__ vtb) {
    int mt = bx & 63, nt = bx >> 6;
    int tid = threadIdx.x, w = tid >> 6, lane = tid & 63;
    int g = lane >> 4, c = lane & 15;

    const __hip_bfloat16* ap = xb + (mt * 64 + w * 16 + c) * 256 + g * 8;
    bf16x8 a[8];
    #pragma unroll
    for (int ks = 0; ks < 8; ++ks) a[ks] = *reinterpret_cast<const bf16x8*>(ap + ks * 32);

    f32x4 acc[4];
    #pragma unroll
    for (int jf = 0; jf < 4; ++jf) { acc[jf][0] = 0.f; acc[jf][1] = 0.f; acc[jf][2] = 0.f; acc[jf][3] = 0.f; }

    const __hip_bfloat16* bp = Wt + (nt * 64 + c) * 256 + g * 8;
    #pragma unroll
    for (int jf = 0; jf < 4; ++jf) {
        const __hip_bfloat16* bpj = bp + jf * 16 * 256;
        #pragma unroll
        for (int ks = 0; ks < 8; ++ks) {
            bf16x8 bfrag = *reinterpret_cast<const bf16x8*>(bpj + ks * 32);
            acc[jf] = __builtin_amdgcn_mfma_f32_16x16x32_bf16(a[ks], bfrag, acc[jf], 0, 0, 0);
        }
    }

    int col0 = nt * 64;
    int part = col0 >> 9;            // 0=q,1=k,2=v
    int h = (col0 >> 6) & 7;
    #pragma unroll
    for (int jf = 0; jf < 4; ++jf) {
        int d = jf * 16 + c;
        #pragma unroll
        for (int r = 0; r < 4; ++r) {
            int m = mt * 64 + w * 16 + g * 4 + r;
            int b = m >> 10, nn = m & 1023;
            if (part == 0)
                qb[(((b * HEADS + h) * NN) + nn) * DH + d] = __float2bfloat16(acc[jf][r] * 0.125f);
            else if (part == 1)
                kb[(((b * HEADS + h) * NN) + nn) * DH + d] = __float2bfloat16(acc[jf][r]);
            else
                vtb[((long)(b * HEADS + h) * DH + d) * NN + nn] = __float2bfloat16(acc[jf][r]);
        }
    }
}

// dmlp, packed f16, 4 independent chains (2 rows x 2 j-groups), weights in LDS.
__device__ __forceinline__ void dmlp_body(int bx,
                                          const float* __restrict__ xyz,
                                          const unsigned int* __restrict__ wlds_u,
                                          _Float16* __restrict__ md) {
    int tid = threadIdx.x;
    int bi0 = bx * 2;                  // rows bi0, bi0+1 (same batch: N even)
    int b = bi0 >> 10;
    const float* xj = xyz + (long)b * NN * 3;

    float xia[2], xib[2], xic[2];
    #pragma unroll
    for (int rr = 0; rr < 2; ++rr) {
        xia[rr] = xyz[(bi0 + rr) * 3 + 0];
        xib[rr] = xyz[(bi0 + rr) * 3 + 1];
        xic[rr] = xyz[(bi0 + rr) * 3 + 2];
    }

    const h2* w = (const h2*)wlds_u;   // LDS-resident splat weights

    // chains indexed cg = rr*2 + g; j = 2*tid + g*512
    h2 d0[4], d1[4], d2[4];
    #pragma unroll
    for (int g = 0; g < 2; ++g) {
        int j = 2 * tid + g * 512;
        const float* pj = xj + j * 3;
        float e0 = pj[0], e1 = pj[1], e2 = pj[2];
        float f0 = pj[3], f1 = pj[4], f2 = pj[5];
        #pragma unroll
        for (int rr = 0; rr < 2; ++rr) {
            int cg = rr * 2 + g;
            d0[cg].x = (_Float16)(e0 - xia[rr]); d0[cg].y = (_Float16)(f0 - xia[rr]);
            d1[cg].x = (_Float16)(e1 - xib[rr]); d1[cg].y = (_Float16)(f1 - xib[rr]);
            d2[cg].x = (_Float16)(e2 - xic[rr]); d2[cg].y = (_Float16)(f2 - xic[rr]);
        }
    }

    h2 pp0[4], pp1[4], pp2[4], nv0[4], nv1[4], nv2[4];
    {   // pos branch
        h2 r0[4], r1[4], r2[4], a0[4], a1[4], a2[4];
        #pragma unroll
        for (int cg = 0; cg < 4; ++cg) {
            r0[cg] = __builtin_elementwise_max(d0[cg], h2s(0.f));
            r1[cg] = __builtin_elementwise_max(d1[cg], h2s(0.f));
            r2[cg] = __builtin_elementwise_max(d2[cg], h2s(0.f));
            a0[cg] = h2s(0.f); a1[cg] = h2s(0.f); a2[cg] = h2s(0.f);
        }
        #pragma unroll
        for (int m = 0; m < 16; ++m) {
            h2 w0 = w[m], w1 = w[16 + m], w2 = w[32 + m];
            h2 u0 = w[48 + 3 * m], u1 = w[48 + 3 * m + 1], u2 = w[48 + 3 * m + 2];
            #pragma unroll
            for (int cg = 0; cg < 4; ++cg) {
                h2 t = r0[cg] * w0 + r1[cg] * w1 + r2[cg] * w2;
                t = gelu_h2(t);
                a0[cg] = a0[cg] + t * u0;
                a1[cg] = a1[cg] + t * u1;
                a2[cg] = a2[cg] + t * u2;
            }
        }
        #pragma unroll
        for (int cg = 0; cg < 4; ++cg) {
            pp0[cg] = leaky_h2(a0[cg]); pp1[cg] = leaky_h2(a1[cg]); pp2[cg] = leaky_h2(a2[cg]);
        }
    }
    {   // neg branch
        h2 r0[4], r1[4], r2[4], a0[4], a1[4], a2[4];
        #pragma unroll
        for (int cg = 0; cg < 4; ++cg) {
            r0[cg] = __builtin_elementwise_max(h2s(0.f) - d0[cg], h2s(0.f));
            r1[cg] = __builtin_elementwise_max(h2s(0.f) - d1[cg], h2s(0.f));
            r2[cg] = __builtin_elementwise_max(h2s(0.f) - d2[cg], h2s(0.f));
            a0[cg] = h2s(0.f); a1[cg] = h2s(0.f); a2[cg] = h2s(0.f);
        }
        #pragma unroll
        for (int m = 0; m < 16; ++m) {
            h2 w0 = w[96 + m], w1 = w[96 + 16 + m], w2 = w[96 + 32 + m];
            h2 u0 = w[144 + 3 * m], u1 = w[144 + 3 * m + 1], u2 = w[144 + 3 * m + 2];
            #pragma unroll
            for (int cg = 0; cg < 4; ++cg) {
                h2 t = r0[cg] * w0 + r1[cg] * w1 + r2[cg] * w2;
                t = gelu_h2(t);
                a0[cg] = a0[cg] + t * u0;
                a1[cg] = a1[cg] + t * u1;
                a2[cg] = a2[cg] + t * u2;
            }
        }
        #pragma unroll
        for (int cg = 0; cg < 4; ++cg) {
            nv0[cg] = leaky_h2(a0[cg]); nv1[cg] = leaky_h2(a1[cg]); nv2[cg] = leaky_h2(a2[cg]);
        }
    }

    h2 c00 = w[192], c01 = w[193], c02 = w[194];
    h2 c10 = w[195], c11 = w[196], c12 = w[197];
    h2 c20 = w[198], c21 = w[199], c22 = w[200];
    h2 b0 = w[201], b1 = w[202], b2 = w[203];

    unsigned int* st0 = (unsigned int*)md;
    unsigned int* st1 = (unsigned int*)(md + MDPLANE);
    unsigned int* st2 = (unsigned int*)(md + 2 * MDPLANE);
    #pragma unroll
    for (int rr = 0; rr < 2; ++rr) {
        long dwbase = (long)(bi0 + rr) * 512;
        #pragma unroll
        for (int g = 0; g < 2; ++g) {
            int cg = rr * 2 + g;
            h2 q0 = pp0[cg] * nv0[cg], q1 = pp1[cg] * nv1[cg], q2 = pp2[cg] * nv2[cg];
            h2 c0 = leaky_h2(q0 * c00 + q1 * c10 + q2 * c20 + b0);
            h2 c1 = leaky_h2(q0 * c01 + q1 * c11 + q2 * c21 + b1);
            h2 c2 = leaky_h2(q0 * c02 + q1 * c12 + q2 * c22 + b2);
            h2 m0 = c0 * d0[cg], m1 = c1 * d1[cg], m2 = c2 * d2[cg];
            long idx = dwbase + tid + g * 256;
            st0[idx] = __builtin_bit_cast(unsigned int, m0);
            st1[idx] = __builtin_bit_cast(unsigned int, m1);
            st2[idx] = __builtin_bit_cast(unsigned int, m2);
        }
    }
}

__global__ __launch_bounds__(256, 4) void fused_mid(const float* __restrict__ xyz,
                                                    const unsigned int* __restrict__ wh,
                                                    _Float16* __restrict__ md,
                                                    const __hip_bfloat16* __restrict__ xb,
                                                    const __hip_bfloat16* __restrict__ Wt,
                                                    __hip_bfloat16* __restrict__ qb,
                                                    __hip_bfloat16* __restrict__ kb,
                                                    __hip_bfloat16* __restrict__ vtb) {
    __shared__ unsigned int wlds[204];
    int bx = blockIdx.x;
    if (bx < 2048) {
        if (threadIdx.x < 204) wlds[threadIdx.x] = wh[threadIdx.x];
        __syncthreads();
        dmlp_body(bx, xyz, wlds, md);
    } else {
        qkv_body(bx - 2048, xb, Wt, qb, kb, vtb);
    }
}

// ---------------- K4: fused MFMA attention (f16 md, hoisted loads) ----------------
__global__ __launch_bounds__(256) void attn_kernel(
    const __hip_bfloat16* __restrict__ q,
    const __hip_bfloat16* __restrict__ kk,
    const __hip_bfloat16* __restrict__ vt,
    const _Float16* __restrict__ md,
    const float* __restrict__ Wsp,
    __hip_bfloat16* __restrict__ yb)
{
    int it = blockIdx.x, h = blockIdx.y, b = blockIdx.z;
    int tid = threadIdx.x;
    int w = tid >> 6, lane = tid & 63;
    int g = lane >> 4, c = lane & 15;

    __shared__ __align__(16) __hip_bfloat16 k_lds[2][64][64];
    __shared__ __align__(16) __hip_bfloat16 v_lds[2][64][64];   // V^T tile: [d][j]
    __shared__ __align__(16) __hip_bfloat16 p_lds[4][16][64];

    const __hip_bfloat16* qp = q + ((long)(b * HEADS + h) * NN + it * 64) * DH;
    const __hip_bfloat16* kp = kk + (long)(b * HEADS + h) * NN * DH;
    const __hip_bfloat16* vp = vt + (long)(b * HEADS + h) * DH * NN;

    bf16x8 qa[2];
    #pragma unroll
    for (int t2 = 0; t2 < 2; ++t2)
        qa[t2] = *reinterpret_cast<const bf16x8*>(qp + (w * 16 + c) * DH + t2 * 32 + g * 8);

    int r0 = tid >> 3;
    int d00 = (tid & 7) * 8;
    int4 kreg[2], vreg[2];

    f32x4 o[4];
    #pragma unroll
    for (int df = 0; df < 4; ++df) { o[df][0] = 0.f; o[df][1] = 0.f; o[df][2] = 0.f; o[df][3] = 0.f; }
    float m_[4] = {-1e30f, -1e30f, -1e30f, -1e30f};
    float l_[4] = {0.f, 0.f, 0.f, 0.f};
    float wdx[4] = {0.f, 0.f, 0.f, 0.f}, wdy[4] = {0.f, 0.f, 0.f, 0.f}, wdz[4] = {0.f, 0.f, 0.f, 0.f};

    #pragma unroll
    for (int c2 = 0; c2 < 2; ++c2) {
        int r = r0 + c2 * 32;
        kreg[c2] = *reinterpret_cast<const int4*>(kp + (0 * 64 + r) * DH + d00);
        vreg[c2] = *reinterpret_cast<const int4*>(vp + (long)r * NN + 0 * 64 + d00);
    }
    #pragma unroll
    for (int c2 = 0; c2 < 2; ++c2) {
        int r = r0 + c2 * 32;
        int sd = d00 ^ ((r & 7) << 3);
        *reinterpret_cast<int4*>(&k_lds[0][r][sd]) = kreg[c2];
        *reinterpret_cast<int4*>(&v_lds[0][r][sd]) = vreg[c2];
    }
    __syncthreads();

    const _Float16* md0 = md;
    const _Float16* md1 = md + MDPLANE;
    const _Float16* md2 = md + 2 * MDPLANE;
    long mdrow = (long)(b * NN + it * 64 + w * 16 + g * 4) * NN + c;

    for (int t = 0; t < NT; ++t) {
        int buf = t & 1;
        if (t + 1 < NT) {
            #pragma unroll
            for (int c2 = 0; c2 < 2; ++c2) {
                int r = r0 + c2 * 32;
                kreg[c2] = *reinterpret_cast<const int4*>(kp + ((t + 1) * 64 + r) * DH + d00);
                vreg[c2] = *reinterpret_cast<const int4*>(vp + (long)r * NN + (t + 1) * 64 + d00);
            }
        }

        // hoisted current-tile md loads (issue early; consumed at wdelta)
        float mdc[4][4][3];
        #pragma unroll
        for (int r = 0; r < 4; ++r) {
            long off = mdrow + (long)r * NN + t * 64;
            #pragma unroll
            for (int jf = 0; jf < 4; ++jf) {
                mdc[r][jf][0] = (float)md0[off + jf * 16];
                mdc[r][jf][1] = (float)md1[off + jf * 16];
                mdc[r][jf][2] = (float)md2[off + jf * 16];
            }
        }

        f32x4 s[4];
        #pragma unroll
        for (int jf = 0; jf < 4; ++jf) {
            f32x4 acc = {0.f, 0.f, 0.f, 0.f};
            int jl = jf * 16 + c;
            int sw = (jl & 7) << 3;
            #pragma unroll
            for (int t2 = 0; t2 < 2; ++t2) {
                bf16x8 bk = *reinterpret_cast<const bf16x8*>(&k_lds[buf][jl][(t2 * 32 + g * 8) ^ sw]);
                acc = __builtin_amdgcn_mfma_f32_16x16x32_bf16(qa[t2], bk, acc, 0, 0, 0);
            }
            s[jf] = acc;
        }

        float pe[4][4];
        #pragma unroll
        for (int r = 0; r < 4; ++r) {
            float tm = fmaxf(fmaxf(s[0][r], s[1][r]), fmaxf(s[2][r], s[3][r]));
            tm = fmaxf(tm, __shfl_xor(tm, 1));
            tm = fmaxf(tm, __shfl_xor(tm, 2));
            tm = fmaxf(tm, __shfl_xor(tm, 4));
            tm = fmaxf(tm, __shfl_xor(tm, 8));
            float nm = fmaxf(m_[r], tm);
            float corr = __expf(m_[r] - nm);
            m_[r] = nm;
            l_[r] *= corr;
            wdx[r] *= corr; wdy[r] *= corr; wdz[r] *= corr;
            o[0][r] *= corr; o[1][r] *= corr; o[2][r] *= corr; o[3][r] *= corr;
            float ps = 0.f;
            #pragma unroll
            for (int jf = 0; jf < 4; ++jf) {
                float p = __expf(s[jf][r] - nm);
                pe[r][jf] = p;
                ps += p;
            }
            l_[r] += ps;
        }

        #pragma unroll
        for (int r = 0; r < 4; ++r) {
            int row = g * 4 + r;
            int sw = (row & 7) << 3;
            #pragma unroll
            for (int jf = 0; jf < 4; ++jf)
                p_lds[w][row][(jf * 16 + c) ^ sw] = __float2bfloat16(pe[r][jf]);
        }
        asm volatile("s_waitcnt lgkmcnt(0)" ::: "memory");

        #pragma unroll
        for (int r = 0; r < 4; ++r) {
            #pragma unroll
            for (int jf = 0; jf < 4; ++jf) {
                wdx[r] = fmaf(pe[r][jf], mdc[r][jf][0], wdx[r]);
                wdy[r] = fmaf(pe[r][jf], mdc[r][jf][1], wdy[r]);
                wdz[r] = fmaf(pe[r][jf], mdc[r][jf][2], wdz[r]);
            }
        }

        #pragma unroll
        for (int t2 = 0; t2 < 2; ++t2) {
            int swp = (c & 7) << 3;
            bf16x8 pa = *reinterpret_cast<const bf16x8*>(&p_lds[w][c][(t2 * 32 + g * 8) ^ swp]);
            #pragma unroll
            for (int df = 0; df < 4; ++df) {
                int dl = df * 16 + c;
                int swv = (dl & 7) << 3;
                bf16x8 bv = *reinterpret_cast<const bf16x8*>(&v_lds[buf][dl][(t2 * 32 + g * 8) ^ swv]);
                o[df] = __builtin_amdgcn_mfma_f32_16x16x32_bf16(pa, bv, o[df], 0, 0, 0);
            }
        }

        if (t + 1 < NT) {
            #pragma unroll
            for (int c2 = 0; c2 < 2; ++c2) {
                int r = r0 + c2 * 32;
                int sd = d00 ^ ((r & 7) << 3);
                *reinterpret_cast<int4*>(&k_lds[buf ^ 1][r][sd]) = kreg[c2];
                *reinterpret_cast<int4*>(&v_lds[buf ^ 1][r][sd]) = vreg[c2];
            }
        }
        __syncthreads();
    }

    #pragma unroll
    for (int r = 0; r < 4; ++r) {
        float lv = l_[r];
        lv += __shfl_xor(lv, 1); lv += __shfl_xor(lv, 2);
        lv += __shfl_xor(lv, 4); lv += __shfl_xor(lv, 8);
        float w0 = wdx[r], w1 = wdy[r], w2 = wdz[r];
        w0 += __shfl_xor(w0, 1); w0 += __shfl_xor(w0, 2); w0 += __shfl_xor(w0, 4); w0 += __shfl_xor(w0, 8);
        w1 += __shfl_xor(w1, 1); w1 += __shfl_xor(w1, 2); w1 += __shfl_xor(w1, 4); w1 += __shfl_xor(w1, 8);
        w2 += __shfl_xor(w2, 1); w2 += __shfl_xor(w2, 2); w2 += __shfl_xor(w2, 4); w2 += __shfl_xor(w2, 8);
        float inv = 1.0f / lv;
        w0 *= inv; w1 *= inv; w2 *= inv;
        int row = g * 4 + r;
        long ig = (long)b * NN + it * 64 + w * 16 + row;
        __hip_bfloat16* yp = yb + ig * INNERD + h * DH;
        #pragma unroll
        for (int df = 0; df < 4; ++df) {
            int d = df * 16 + c;
            float disp = w0 * Wsp[d] + w1 * Wsp[64 + d] + w2 * Wsp[128 + d];
            yp[d] = __float2bfloat16(o[df][r] * inv + disp);
        }
    }
}

// ---------------- K5: MFMA output projection + GELU + residual ----------------
__global__ __launch_bounds__(256) void out_gemm(const __hip_bfloat16* __restrict__ yb,
                                                const __hip_bfloat16* __restrict__ Wot,
                                                const float* __restrict__ bout,
                                                const float* __restrict__ feat,
                                                float* __restrict__ out) {
    int mt = blockIdx.x, nt = blockIdx.y;
    int tid = threadIdx.x, w = tid >> 6, lane = tid & 63;
    int g = lane >> 4, c = lane & 15;

    const __hip_bfloat16* ap = yb + ((long)mt * 64 + w * 16 + c) * INNERD + g * 8;
    bf16x8 a[16];
    #pragma unroll
    for (int ks = 0; ks < 16; ++ks) a[ks] = *reinterpret_cast<const bf16x8*>(ap + ks * 32);

    f32x4 acc[4];
    #pragma unroll
    for (int jf = 0; jf < 4; ++jf) { acc[jf][0] = 0.f; acc[jf][1] = 0.f; acc[jf][2] = 0.f; acc[jf][3] = 0.f; }

    const __hip_bfloat16* bp = Wot + (nt * 64 + c) * INNERD + g * 8;
    #pragma unroll
    for (int jf = 0; jf < 4; ++jf) {
        const __hip_bfloat16* bpj = bp + jf * 16 * INNERD;
        #pragma unroll
        for (int ks = 0; ks < 16; ++ks) {
            bf16x8 bfrag = *reinterpret_cast<const bf16x8*>(bpj + ks * 32);
            acc[jf] = __builtin_amdgcn_mfma_f32_16x16x32_bf16(a[ks], bfrag, acc[jf], 0, 0, 0);
        }
    }

    #pragma unroll
    for (int jf = 0; jf < 4; ++jf) {
        int d = nt * 64 + jf * 16 + c;
        float bo = bout[d];
        #pragma unroll
        for (int r = 0; r < 4; ++r) {
            long m = (long)mt * 64 + w * 16 + g * 4 + r;
            float val = gelu_poly(acc[jf][r] + bo);
            out[m * DIMM + d] = val + feat[m * DIMM + d];
        }
    }
}

extern "C" void kernel_launch(void* const* d_in, const int* in_sizes, int n_in,
                              void* d_out, int out_size, void* d_ws, size_t ws_size,
                              hipStream_t stream) {
    const float* xyzs  = (const float*)d_in[0];
    const float* feat  = (const float*)d_in[1];
    const float* gamma = (const float*)d_in[2];
    const float* beta  = (const float*)d_in[3];
    const float* Wqkv  = (const float*)d_in[4];
    const float* Wp1   = (const float*)d_in[5];
    const float* Wp2   = (const float*)d_in[6];
    const float* Wn1   = (const float*)d_in[7];
    const float* Wn2   = (const float*)d_in[8];
    const float* Wc    = (const float*)d_in[9];
    const float* bc    = (const float*)d_in[10];
    const float* Wsp   = (const float*)d_in[11];
    const float* Wout  = (const float*)d_in[12];
    const float* bout  = (const float*)d_in[13];
    float* out = (float*)d_out;

    // workspace: xb 1M bf16 | Wt 384K bf16 | Wot 128K bf16 | qb/kb/vtb/yb 2M bf16 each | md 12M f16 | wh 204 u32
    __hip_bfloat16* xb  = (__hip_bfloat16*)d_ws;
    __hip_bfloat16* Wt  = xb + 1048576;
    __hip_bfloat16* Wot = Wt + 393216;
    __hip_bfloat16* qb  = Wot + 131072;
    __hip_bfloat16* kb  = qb + 2097152;
    __hip_bfloat16* vtb = kb + 2097152;
    __hip_bfloat16* yb  = vtb + 2097152;
    _Float16* md = (_Float16*)(yb + 2097152);
    unsigned int* wh = (unsigned int*)(md + 3 * MDPLANE);

    prep_kernel<<<4225, 256, 0, stream>>>(feat, gamma, beta, xb, Wqkv, Wt, Wout, Wot,
                                          Wp1, Wp2, Wn1, Wn2, Wc, bc, wh);
    fused_mid<<<3584, 256, 0, stream>>>(xyzs, wh, md, xb, Wt, qb, kb, vtb);
    attn_kernel<<<dim3(16, HEADS, BB), 256, 0, stream>>>(qb, kb, vtb, md, Wsp, yb);
    out_gemm<<<dim3(64, 4), 256, 0, stream>>>(yb, Wot, bout, feat, out);
}

// Round 13
// 118.632 us; speedup vs baseline: 1.4530x; 1.0436x over previous
//
#include <hip/hip_runtime.h>
#include <hip/hip_bf16.h>
#include <math.h>

#define BB 4
#define NN 1024
#define DIMM 256
#define HEADS 8
#define DH 64
#define INNERD 512
#define NT 16
#define MDPLANE 4194304   // B*N*N

typedef __bf16 bf16x8 __attribute__((ext_vector_type(8)));
typedef float f32x4 __attribute__((ext_vector_type(4)));
typedef _Float16 h2 __attribute__((ext_vector_type(2)));

__device__ __forceinline__ h2 h2s(float v) {
    _Float16 h = (_Float16)v;
    h2 r; r.x = h; r.y = h;
    return r;
}

// Trans-free GELU (f32, out_gemm epilogue): clamp [-3,3] + odd poly.
__device__ __forceinline__ float gelu_poly(float x) {
    float xc = fminf(fmaxf(x, -3.0f), 3.0f);
    float u = xc * xc;
    float f = fmaf(u, fmaf(u, fmaf(u, fmaf(u, 4.4413e-5f, -1.33195e-3f),
                                   1.70980e-2f), -1.299964e-1f), 7.9734583e-1f);
    float E = xc * f;
    float hx = 0.5f * xc;
    float g = fmaf(hx, E, hx);
    return g + fmaxf(x - 3.0f, 0.0f);
}

// Packed-f16 GELU (trans-free): gelu(xc) = 0.5*xc + u*f2(u), coeffs pre-halved.
__device__ __forceinline__ h2 gelu_h2(h2 x) {
    h2 xc = __builtin_elementwise_min(__builtin_elementwise_max(x, h2s(-3.0f)), h2s(3.0f));
    h2 u = xc * xc;
    h2 f = u * h2s(2.22065e-5f) + h2s(-6.65975e-4f);
    f = u * f + h2s(8.549e-3f);
    f = u * f + h2s(-6.49982e-2f);
    f = u * f + h2s(0.39867292f);
    h2 g = xc * h2s(0.5f) + u * f;
    h2 tail = __builtin_elementwise_max(x - h2s(3.0f), h2s(0.0f));
    return g + tail;
}
__device__ __forceinline__ h2 leaky_h2(h2 x) {
    return __builtin_elementwise_max(x, x * h2s(0.01f));
}

// ---------------- prep: ln (0..4095) | wtg Wqkv (4096..4191) | wtg Wout (4192..4223) | wh (4224) ----------------
__global__ __launch_bounds__(256) void prep_kernel(const float* __restrict__ feat,
                                                   const float* __restrict__ gamma,
                                                   const float* __restrict__ beta,
                                                   __hip_bfloat16* __restrict__ xb,
                                                   const float* __restrict__ Wqkv,
                                                   __hip_bfloat16* __restrict__ Wt,
                                                   const float* __restrict__ Wout,
                                                   __hip_bfloat16* __restrict__ Wot,
                                                   const float* __restrict__ Wp1,
                                                   const float* __restrict__ Wp2,
                                                   const float* __restrict__ Wn1,
                                                   const float* __restrict__ Wn2,
                                                   const float* __restrict__ Wc,
                                                   const float* __restrict__ bc,
                                                   unsigned int* __restrict__ wh) {
    __shared__ float smem[64 * 65];
    int bx = blockIdx.x;
    int tid = threadIdx.x;
    if (bx < 4096) {
        int row = bx;
        float v = feat[row * DIMM + tid];
        float s = v, ss = v * v;
        #pragma unroll
        for (int off = 1; off < 64; off <<= 1) {
            s += __shfl_xor(s, off);
            ss += __shfl_xor(ss, off);
        }
        float* red = smem;
        int w = tid >> 6, lane = tid & 63;
        if (lane == 0) { red[w] = s; red[4 + w] = ss; }
        __syncthreads();
        s = red[0] + red[1] + red[2] + red[3];
        ss = red[4] + red[5] + red[6] + red[7];
        float mu = s * (1.0f / DIMM);
        float var = ss * (1.0f / DIMM) - mu * mu;
        float rs = rsqrtf(var + 1e-5f);
        xb[row * DIMM + tid] = __float2bfloat16((v - mu) * rs * gamma[tid] + beta[tid]);
    } else if (bx < 4224) {
        const float* W;
        __hip_bfloat16* Wd;
        int C, R, nx, ky;
        if (bx < 4192) {
            int t = bx - 4096;          // 96 tiles: 24 x 4
            W = Wqkv; Wd = Wt; C = 1536; R = 256;
            nx = t % 24; ky = t / 24;
        } else {
            int t = bx - 4192;          // 32 tiles: 4 x 8
            W = Wout; Wd = Wot; C = 256; R = 512;
            nx = t % 4; ky = t / 4;
        }
        int n0 = nx * 64, k0 = ky * 64;
        int cc = tid & 63, rr = tid >> 6;
        #pragma unroll
        for (int p = 0; p < 16; ++p) {
            int k = rr + p * 4;
            smem[k * 65 + cc] = W[(k0 + k) * C + n0 + cc];
        }
        __syncthreads();
        #pragma unroll
        for (int p = 0; p < 16; ++p) {
            int n = rr + p * 4;
            Wd[(n0 + n) * R + k0 + cc] = __float2bfloat16(smem[cc * 65 + n]);
        }
    } else {
        // splat-convert dmlp weights to h2 uints
        int t = tid;
        if (t < 204) {
            float v;
            if (t < 48) v = Wp1[t];
            else if (t < 96) v = Wp2[t - 48];
            else if (t < 144) v = Wn1[t - 96];
            else if (t < 192) v = Wn2[t - 144];
            else if (t < 201) v = Wc[t - 192];
            else v = bc[t - 201];
            _Float16 h = (_Float16)v;
            unsigned short us = __builtin_bit_cast(unsigned short, h);
            wh[t] = (unsigned int)us | ((unsigned int)us << 16);
        }
    }
}

// ---------------- fused mid: dmlp blocks (0..1023, 4 rows each) || qkv GEMM (1024..2559) ----------------
__device__ __forceinline__ void qkv_body(int bx,
                                         const __hip_bfloat16* __restrict__ xb,
                                         const __hip_bfloat16* __restrict__ Wt,
                                         __hip_bfloat16* __restrict__ qb,
                                         __hip_bfloat16* __restrict__ kb,
                                         __hip_bfloat16* __restrict__ vtb) {
    int mt = bx & 63, nt = bx >> 6;
    int tid = threadIdx.x, w = tid >> 6, lane = tid & 63;
    int g = lane >> 4, c = lane & 15;

    const __hip_bfloat16* ap = xb + (mt * 64 + w * 16 + c) * 256 + g * 8;
    bf16x8 a[8];
    #pragma unroll
    for (int ks = 0; ks < 8; ++ks) a[ks] = *reinterpret_cast<const bf16x8*>(ap + ks * 32);

    f32x4 acc[4];
    #pragma unroll
    for (int jf = 0; jf < 4; ++jf) { acc[jf][0] = 0.f; acc[jf][1] = 0.f; acc[jf][2] = 0.f; acc[jf][3] = 0.f; }

    const __hip_bfloat16* bp = Wt + (nt * 64 + c) * 256 + g * 8;
    #pragma unroll
    for (int jf = 0; jf < 4; ++jf) {
        const __hip_bfloat16* bpj = bp + jf * 16 * 256;
        #pragma unroll
        for (int ks = 0; ks < 8; ++ks) {
            bf16x8 bfrag = *reinterpret_cast<const bf16x8*>(bpj + ks * 32);
            acc[jf] = __builtin_amdgcn_mfma_f32_16x16x32_bf16(a[ks], bfrag, acc[jf], 0, 0, 0);
        }
    }

    int col0 = nt * 64;
    int part = col0 >> 9;            // 0=q,1=k,2=v
    int h = (col0 >> 6) & 7;
    #pragma unroll
    for (int jf = 0; jf < 4; ++jf) {
        int d = jf * 16 + c;
        #pragma unroll
        for (int r = 0; r < 4; ++r) {
            int m = mt * 64 + w * 16 + g * 4 + r;
            int b = m >> 10, nn = m & 1023;
            if (part == 0)
                qb[(((b * HEADS + h) * NN) + nn) * DH + d] = __float2bfloat16(acc[jf][r] * 0.125f);
            else if (part == 1)
                kb[(((b * HEADS + h) * NN) + nn) * DH + d] = __float2bfloat16(acc[jf][r]);
            else
                vtb[((long)(b * HEADS + h) * DH + d) * NN + nn] = __float2bfloat16(acc[jf][r]);
        }
    }
}

// dmlp, packed f16, 8 independent chains (4 rows x 2 j-groups), weights in LDS.
// Hypothesis under test: pk-f16 dep latency ~8cy needs 8 chains to saturate issue.
__device__ __forceinline__ void dmlp_body(int bx,
                                          const float* __restrict__ xyz,
                                          const unsigned int* __restrict__ wlds_u,
                                          _Float16* __restrict__ md) {
    int tid = threadIdx.x;
    int bi0 = bx * 4;                  // rows bi0..bi0+3 (same batch: N % 4 == 0)
    int b = bi0 >> 10;
    const float* xj = xyz + (long)b * NN * 3;

    float xia[4], xib[4], xic[4];
    #pragma unroll
    for (int rr = 0; rr < 4; ++rr) {
        xia[rr] = xyz[(bi0 + rr) * 3 + 0];
        xib[rr] = xyz[(bi0 + rr) * 3 + 1];
        xic[rr] = xyz[(bi0 + rr) * 3 + 2];
    }

    const h2* w = (const h2*)wlds_u;   // LDS-resident splat weights

    // chains indexed cg = rr*2 + g; j = 2*tid + g*512
    h2 d0[8], d1[8], d2[8];
    #pragma unroll
    for (int g = 0; g < 2; ++g) {
        int j = 2 * tid + g * 512;
        const float* pj = xj + j * 3;
        float e0 = pj[0], e1 = pj[1], e2 = pj[2];
        float f0 = pj[3], f1 = pj[4], f2 = pj[5];
        #pragma unroll
        for (int rr = 0; rr < 4; ++rr) {
            int cg = rr * 2 + g;
            d0[cg].x = (_Float16)(e0 - xia[rr]); d0[cg].y = (_Float16)(f0 - xia[rr]);
            d1[cg].x = (_Float16)(e1 - xib[rr]); d1[cg].y = (_Float16)(f1 - xib[rr]);
            d2[cg].x = (_Float16)(e2 - xic[rr]); d2[cg].y = (_Float16)(f2 - xic[rr]);
        }
    }

    h2 pp0[8], pp1[8], pp2[8], nv0[8], nv1[8], nv2[8];
    {   // pos branch
        h2 r0[8], r1[8], r2[8], a0[8], a1[8], a2[8];
        #pragma unroll
        for (int cg = 0; cg < 8; ++cg) {
            r0[cg] = __builtin_elementwise_max(d0[cg], h2s(0.f));
            r1[cg] = __builtin_elementwise_max(d1[cg], h2s(0.f));
            r2[cg] = __builtin_elementwise_max(d2[cg], h2s(0.f));
            a0[cg] = h2s(0.f); a1[cg] = h2s(0.f); a2[cg] = h2s(0.f);
        }
        #pragma unroll
        for (int m = 0; m < 16; ++m) {
            h2 w0 = w[m], w1 = w[16 + m], w2 = w[32 + m];
            h2 u0 = w[48 + 3 * m], u1 = w[48 + 3 * m + 1], u2 = w[48 + 3 * m + 2];
            #pragma unroll
            for (int cg = 0; cg < 8; ++cg) {
                h2 t = r0[cg] * w0 + r1[cg] * w1 + r2[cg] * w2;
                t = gelu_h2(t);
                a0[cg] = a0[cg] + t * u0;
                a1[cg] = a1[cg] + t * u1;
                a2[cg] = a2[cg] + t * u2;
            }
        }
        #pragma unroll
        for (int cg = 0; cg < 8; ++cg) {
            pp0[cg] = leaky_h2(a0[cg]); pp1[cg] = leaky_h2(a1[cg]); pp2[cg] = leaky_h2(a2[cg]);
        }
    }
    {   // neg branch
        h2 r0[8], r1[8], r2[8], a0[8], a1[8], a2[8];
        #pragma unroll
        for (int cg = 0; cg < 8; ++cg) {
            r0[cg] = __builtin_elementwise_max(h2s(0.f) - d0[cg], h2s(0.f));
            r1[cg] = __builtin_elementwise_max(h2s(0.f) - d1[cg], h2s(0.f));
            r2[cg] = __builtin_elementwise_max(h2s(0.f) - d2[cg], h2s(0.f));
            a0[cg] = h2s(0.f); a1[cg] = h2s(0.f); a2[cg] = h2s(0.f);
        }
        #pragma unroll
        for (int m = 0; m < 16; ++m) {
            h2 w0 = w[96 + m], w1 = w[96 + 16 + m], w2 = w[96 + 32 + m];
            h2 u0 = w[144 + 3 * m], u1 = w[144 + 3 * m + 1], u2 = w[144 + 3 * m + 2];
            #pragma unroll
            for (int cg = 0; cg < 8; ++cg) {
                h2 t = r0[cg] * w0 + r1[cg] * w1 + r2[cg] * w2;
                t = gelu_h2(t);
                a0[cg] = a0[cg] + t * u0;
                a1[cg] = a1[cg] + t * u1;
                a2[cg] = a2[cg] + t * u2;
            }
        }
        #pragma unroll
        for (int cg = 0; cg < 8; ++cg) {
            nv0[cg] = leaky_h2(a0[cg]); nv1[cg] = leaky_h2(a1[cg]); nv2[cg] = leaky_h2(a2[cg]);
        }
    }

    h2 c00 = w[192], c01 = w[193], c02 = w[194];
    h2 c10 = w[195], c11 = w[196], c12 = w[197];
    h2 c20 = w[198], c21 = w[199], c22 = w[200];
    h2 b0 = w[201], b1 = w[202], b2 = w[203];

    unsigned int* st0 = (unsigned int*)md;
    unsigned int* st1 = (unsigned int*)(md + MDPLANE);
    unsigned int* st2 = (unsigned int*)(md + 2 * MDPLANE);
    #pragma unroll
    for (int rr = 0; rr < 4; ++rr) {
        long dwbase = (long)(bi0 + rr) * 512;
        #pragma unroll
        for (int g = 0; g < 2; ++g) {
            int cg = rr * 2 + g;
            h2 q0 = pp0[cg] * nv0[cg], q1 = pp1[cg] * nv1[cg], q2 = pp2[cg] * nv2[cg];
            h2 c0 = leaky_h2(q0 * c00 + q1 * c10 + q2 * c20 + b0);
            h2 c1 = leaky_h2(q0 * c01 + q1 * c11 + q2 * c21 + b1);
            h2 c2 = leaky_h2(q0 * c02 + q1 * c12 + q2 * c22 + b2);
            h2 m0 = c0 * d0[cg], m1 = c1 * d1[cg], m2 = c2 * d2[cg];
            long idx = dwbase + tid + g * 256;
            st0[idx] = __builtin_bit_cast(unsigned int, m0);
            st1[idx] = __builtin_bit_cast(unsigned int, m1);
            st2[idx] = __builtin_bit_cast(unsigned int, m2);
        }
    }
}

__global__ __launch_bounds__(256, 4) void fused_mid(const float* __restrict__ xyz,
                                                    const unsigned int* __restrict__ wh,
                                                    _Float16* __restrict__ md,
                                                    const __hip_bfloat16* __restrict__ xb,
                                                    const __hip_bfloat16* __restrict__ Wt,
                                                    __hip_bfloat16* __restrict__ qb,
                                                    __hip_bfloat16* __restrict__ kb,
                                                    __hip_bfloat16* __restrict__ vtb) {
    __shared__ unsigned int wlds[204];
    int bx = blockIdx.x;
    if (bx < 1024) {
        if (threadIdx.x < 204) wlds[threadIdx.x] = wh[threadIdx.x];
        __syncthreads();
        dmlp_body(bx, xyz, wlds, md);
    } else {
        qkv_body(bx - 1024, xb, Wt, qb, kb, vtb);
    }
}

// ---------------- K4: fused MFMA attention (f16 md, hoisted loads) ----------------
__global__ __launch_bounds__(256) void attn_kernel(
    const __hip_bfloat16* __restrict__ q,
    const __hip_bfloat16* __restrict__ kk,
    const __hip_bfloat16* __restrict__ vt,
    const _Float16* __restrict__ md,
    const float* __restrict__ Wsp,
    __hip_bfloat16* __restrict__ yb)
{
    int it = blockIdx.x, h = blockIdx.y, b = blockIdx.z;
    int tid = threadIdx.x;
    int w = tid >> 6, lane = tid & 63;
    int g = lane >> 4, c = lane & 15;

    __shared__ __align__(16) __hip_bfloat16 k_lds[2][64][64];
    __shared__ __align__(16) __hip_bfloat16 v_lds[2][64][64];   // V^T tile: [d][j]
    __shared__ __align__(16) __hip_bfloat16 p_lds[4][16][64];

    const __hip_bfloat16* qp = q + ((long)(b * HEADS + h) * NN + it * 64) * DH;
    const __hip_bfloat16* kp = kk + (long)(b * HEADS + h) * NN * DH;
    const __hip_bfloat16* vp = vt + (long)(b * HEADS + h) * DH * NN;

    bf16x8 qa[2];
    #pragma unroll
    for (int t2 = 0; t2 < 2; ++t2)
        qa[t2] = *reinterpret_cast<const bf16x8*>(qp + (w * 16 + c) * DH + t2 * 32 + g * 8);

    int r0 = tid >> 3;
    int d00 = (tid & 7) * 8;
    int4 kreg[2], vreg[2];

    f32x4 o[4];
    #pragma unroll
    for (int df = 0; df < 4; ++df) { o[df][0] = 0.f; o[df][1] = 0.f; o[df][2] = 0.f; o[df][3] = 0.f; }
    float m_[4] = {-1e30f, -1e30f, -1e30f, -1e30f};
    float l_[4] = {0.f, 0.f, 0.f, 0.f};
    float wdx[4] = {0.f, 0.f, 0.f, 0.f}, wdy[4] = {0.f, 0.f, 0.f, 0.f}, wdz[4] = {0.f, 0.f, 0.f, 0.f};

    #pragma unroll
    for (int c2 = 0; c2 < 2; ++c2) {
        int r = r0 + c2 * 32;
        kreg[c2] = *reinterpret_cast<const int4*>(kp + (0 * 64 + r) * DH + d00);
        vreg[c2] = *reinterpret_cast<const int4*>(vp + (long)r * NN + 0 * 64 + d00);
    }
    #pragma unroll
    for (int c2 = 0; c2 < 2; ++c2) {
        int r = r0 + c2 * 32;
        int sd = d00 ^ ((r & 7) << 3);
        *reinterpret_cast<int4*>(&k_lds[0][r][sd]) = kreg[c2];
        *reinterpret_cast<int4*>(&v_lds[0][r][sd]) = vreg[c2];
    }
    __syncthreads();

    const _Float16* md0 = md;
    const _Float16* md1 = md + MDPLANE;
    const _Float16* md2 = md + 2 * MDPLANE;
    long mdrow = (long)(b * NN + it * 64 + w * 16 + g * 4) * NN + c;

    for (int t = 0; t < NT; ++t) {
        int buf = t & 1;
        if (t + 1 < NT) {
            #pragma unroll
            for (int c2 = 0; c2 < 2; ++c2) {
                int r = r0 + c2 * 32;
                kreg[c2] = *reinterpret_cast<const int4*>(kp + ((t + 1) * 64 + r) * DH + d00);
                vreg[c2] = *reinterpret_cast<const int4*>(vp + (long)r * NN + (t + 1) * 64 + d00);
            }
        }

        // hoisted current-tile md loads (issue early; consumed at wdelta)
        float mdc[4][4][3];
        #pragma unroll
        for (int r = 0; r < 4; ++r) {
            long off = mdrow + (long)r * NN + t * 64;
            #pragma unroll
            for (int jf = 0; jf < 4; ++jf) {
                mdc[r][jf][0] = (float)md0[off + jf * 16];
                mdc[r][jf][1] = (float)md1[off + jf * 16];
                mdc[r][jf][2] = (float)md2[off + jf * 16];
            }
        }

        f32x4 s[4];
        #pragma unroll
        for (int jf = 0; jf < 4; ++jf) {
            f32x4 acc = {0.f, 0.f, 0.f, 0.f};
            int jl = jf * 16 + c;
            int sw = (jl & 7) << 3;
            #pragma unroll
            for (int t2 = 0; t2 < 2; ++t2) {
                bf16x8 bk = *reinterpret_cast<const bf16x8*>(&k_lds[buf][jl][(t2 * 32 + g * 8) ^ sw]);
                acc = __builtin_amdgcn_mfma_f32_16x16x32_bf16(qa[t2], bk, acc, 0, 0, 0);
            }
            s[jf] = acc;
        }

        float pe[4][4];
        #pragma unroll
        for (int r = 0; r < 4; ++r) {
            float tm = fmaxf(fmaxf(s[0][r], s[1][r]), fmaxf(s[2][r], s[3][r]));
            tm = fmaxf(tm, __shfl_xor(tm, 1));
            tm = fmaxf(tm, __shfl_xor(tm, 2));
            tm = fmaxf(tm, __shfl_xor(tm, 4));
            tm = fmaxf(tm, __shfl_xor(tm, 8));
            float nm = fmaxf(m_[r], tm);
            float corr = __expf(m_[r] - nm);
            m_[r] = nm;
            l_[r] *= corr;
            wdx[r] *= corr; wdy[r] *= corr; wdz[r] *= corr;
            o[0][r] *= corr; o[1][r] *= corr; o[2][r] *= corr; o[3][r] *= corr;
            float ps = 0.f;
            #pragma unroll
            for (int jf = 0; jf < 4; ++jf) {
                float p = __expf(s[jf][r] - nm);
                pe[r][jf] = p;
                ps += p;
            }
            l_[r] += ps;
        }

        #pragma unroll
        for (int r = 0; r < 4; ++r) {
            int row = g * 4 + r;
            int sw = (row & 7) << 3;
            #pragma unroll
            for (int jf = 0; jf < 4; ++jf)
                p_lds[w][row][(jf * 16 + c) ^ sw] = __float2bfloat16(pe[r][jf]);
        }
        asm volatile("s_waitcnt lgkmcnt(0)" ::: "memory");

        #pragma unroll
        for (int r = 0; r < 4; ++r) {
            #pragma unroll
            for (int jf = 0; jf < 4; ++jf) {
                wdx[r] = fmaf(pe[r][jf], mdc[r][jf][0], wdx[r]);
                wdy[r] = fmaf(pe[r][jf], mdc[r][jf][1], wdy[r]);
                wdz[r] = fmaf(pe[r][jf], mdc[r][jf][2], wdz[r]);
            }
        }

        #pragma unroll
        for (int t2 = 0; t2 < 2; ++t2) {
            int swp = (c & 7) << 3;
            bf16x8 pa = *reinterpret_cast<const bf16x8*>(&p_lds[w][c][(t2 * 32 + g * 8) ^ swp]);
            #pragma unroll
            for (int df = 0; df < 4; ++df) {
                int dl = df * 16 + c;
                int swv = (dl & 7) << 3;
                bf16x8 bv = *reinterpret_cast<const bf16x8*>(&v_lds[buf][dl][(t2 * 32 + g * 8) ^ swv]);
                o[df] = __builtin_amdgcn_mfma_f32_16x16x32_bf16(pa, bv, o[df], 0, 0, 0);
            }
        }

        if (t + 1 < NT) {
            #pragma unroll
            for (int c2 = 0; c2 < 2; ++c2) {
                int r = r0 + c2 * 32;
                int sd = d00 ^ ((r & 7) << 3);
                *reinterpret_cast<int4*>(&k_lds[buf ^ 1][r][sd]) = kreg[c2];
                *reinterpret_cast<int4*>(&v_lds[buf ^ 1][r][sd]) = vreg[c2];
            }
        }
        __syncthreads();
    }

    #pragma unroll
    for (int r = 0; r < 4; ++r) {
        float lv = l_[r];
        lv += __shfl_xor(lv, 1); lv += __shfl_xor(lv, 2);
        lv += __shfl_xor(lv, 4); lv += __shfl_xor(lv, 8);
        float w0 = wdx[r], w1 = wdy[r], w2 = wdz[r];
        w0 += __shfl_xor(w0, 1); w0 += __shfl_xor(w0, 2); w0 += __shfl_xor(w0, 4); w0 += __shfl_xor(w0, 8);
        w1 += __shfl_xor(w1, 1); w1 += __shfl_xor(w1, 2); w1 += __shfl_xor(w1, 4); w1 += __shfl_xor(w1, 8);
        w2 += __shfl_xor(w2, 1); w2 += __shfl_xor(w2, 2); w2 += __shfl_xor(w2, 4); w2 += __shfl_xor(w2, 8);
        float inv = 1.0f / lv;
        w0 *= inv; w1 *= inv; w2 *= inv;
        int row = g * 4 + r;
        long ig = (long)b * NN + it * 64 + w * 16 + row;
        __hip_bfloat16* yp = yb + ig * INNERD + h * DH;
        #pragma unroll
        for (int df = 0; df < 4; ++df) {
            int d = df * 16 + c;
            float disp = w0 * Wsp[d] + w1 * Wsp[64 + d] + w2 * Wsp[128 + d];
            yp[d] = __float2bfloat16(o[df][r] * inv + disp);
        }
    }
}

// ---------------- K5: MFMA output projection + GELU + residual ----------------
__global__ __launch_bounds__(256) void out_gemm(const __hip_bfloat16* __restrict__ yb,
                                                const __hip_bfloat16* __restrict__ Wot,
                                                const float* __restrict__ bout,
                                                const float* __restrict__ feat,
                                                float* __restrict__ out) {
    int mt = blockIdx.x, nt = blockIdx.y;
    int tid = threadIdx.x, w = tid >> 6, lane = tid & 63;
    int g = lane >> 4, c = lane & 15;

    const __hip_bfloat16* ap = yb + ((long)mt * 64 + w * 16 + c) * INNERD + g * 8;
    bf16x8 a[16];
    #pragma unroll
    for (int ks = 0; ks < 16; ++ks) a[ks] = *reinterpret_cast<const bf16x8*>(ap + ks * 32);

    f32x4 acc[4];
    #pragma unroll
    for (int jf = 0; jf < 4; ++jf) { acc[jf][0] = 0.f; acc[jf][1] = 0.f; acc[jf][2] = 0.f; acc[jf][3] = 0.f; }

    const __hip_bfloat16* bp = Wot + (nt * 64 + c) * INNERD + g * 8;
    #pragma unroll
    for (int jf = 0; jf < 4; ++jf) {
        const __hip_bfloat16* bpj = bp + jf * 16 * INNERD;
        #pragma unroll
        for (int ks = 0; ks < 16; ++ks) {
            bf16x8 bfrag = *reinterpret_cast<const bf16x8*>(bpj + ks * 32);
            acc[jf] = __builtin_amdgcn_mfma_f32_16x16x32_bf16(a[ks], bfrag, acc[jf], 0, 0, 0);
        }
    }

    #pragma unroll
    for (int jf = 0; jf < 4; ++jf) {
        int d = nt * 64 + jf * 16 + c;
        float bo = bout[d];
        #pragma unroll
        for (int r = 0; r < 4; ++r) {
            long m = (long)mt * 64 + w * 16 + g * 4 + r;
            float val = gelu_poly(acc[jf][r] + bo);
            out[m * DIMM + d] = val + feat[m * DIMM + d];
        }
    }
}

extern "C" void kernel_launch(void* const* d_in, const int* in_sizes, int n_in,
                              void* d_out, int out_size, void* d_ws, size_t ws_size,
                              hipStream_t stream) {
    const float* xyzs  = (const float*)d_in[0];
    const float* feat  = (const float*)d_in[1];
    const float* gamma = (const float*)d_in[2];
    const float* beta  = (const float*)d_in[3];
    const float* Wqkv  = (const float*)d_in[4];
    const float* Wp1   = (const float*)d_in[5];
    const float* Wp2   = (const float*)d_in[6];
    const float* Wn1   = (const float*)d_in[7];
    const float* Wn2   = (const float*)d_in[8];
    const float* Wc    = (const float*)d_in[9];
    const float* bc    = (const float*)d_in[10];
    const float* Wsp   = (const float*)d_in[11];
    const float* Wout  = (const float*)d_in[12];
    const float* bout  = (const float*)d_in[13];
    float* out = (float*)d_out;

    // workspace: xb 1M bf16 | Wt 384K bf16 | Wot 128K bf16 | qb/kb/vtb/yb 2M bf16 each | md 12M f16 | wh 204 u32
    __hip_bfloat16* xb  = (__hip_bfloat16*)d_ws;
    __hip_bfloat16* Wt  = xb + 1048576;
    __hip_bfloat16* Wot = Wt + 393216;
    __hip_bfloat16* qb  = Wot + 131072;
    __hip_bfloat16* kb  = qb + 2097152;
    __hip_bfloat16* vtb = kb + 2097152;
    __hip_bfloat16* yb  = vtb + 2097152;
    _Float16* md = (_Float16*)(yb + 2097152);
    unsigned int* wh = (unsigned int*)(md + 3 * MDPLANE);

    prep_kernel<<<4225, 256, 0, stream>>>(feat, gamma, beta, xb, Wqkv, Wt, Wout, Wot,
                                          Wp1, Wp2, Wn1, Wn2, Wc, bc, wh);
    fused_mid<<<2560, 256, 0, stream>>>(xyzs, wh, md, xb, Wt, qb, kb, vtb);
    attn_kernel<<<dim3(16, HEADS, BB), 256, 0, stream>>>(qb, kb, vtb, md, Wsp, yb);
    out_gemm<<<dim3(64, 4), 256, 0, stream>>>(yb, Wot, bout, feat, out);
}